// Round 1
// baseline (529.304 us; speedup 1.0000x reference)
//
#include <hip/hip_runtime.h>

#define DIMC 2048
#define NSEQ 2048
#define NBATCH 2
#define NH 32
#define DH 64
#define BHEADS (NBATCH*NH)      // 64
#define MROWS (NBATCH*NSEQ)     // 4096
#define NQKV (3*DIMC)           // 6144

typedef __attribute__((ext_vector_type(8))) short short8;
typedef __attribute__((ext_vector_type(4))) float f32x4;
typedef __attribute__((ext_vector_type(4))) unsigned int uint4v;

static __device__ __forceinline__ unsigned short f2bf(float f) {
  union { float f; unsigned int u; } v; v.f = f;
  unsigned int r = (v.u + 0x7FFFu + ((v.u >> 16) & 1u)) >> 16;
  return (unsigned short)r;
}

// ---------------- fp32 -> bf16 convert (vectorized, grid-stride) ------------
__global__ __launch_bounds__(256) void cvt_bf16(const float* __restrict__ in,
                                                unsigned short* __restrict__ out,
                                                int n8) {
  int i = blockIdx.x * blockDim.x + threadIdx.x;
  int stride = gridDim.x * blockDim.x;
  for (; i < n8; i += stride) {
    const float4* p = (const float4*)in + (size_t)i * 2;
    float4 a = p[0], b = p[1];
    union { unsigned short u[8]; uint4v v; } o;
    o.u[0] = f2bf(a.x); o.u[1] = f2bf(a.y); o.u[2] = f2bf(a.z); o.u[3] = f2bf(a.w);
    o.u[4] = f2bf(b.x); o.u[5] = f2bf(b.y); o.u[6] = f2bf(b.z); o.u[7] = f2bf(b.w);
    *((uint4v*)out + i) = o.v;
  }
}

// ---------------- cos/sin table --------------------------------------------
__global__ __launch_bounds__(256) void build_cs(const float* __restrict__ freqs,
                                                float2* __restrict__ cs, int n) {
  int i = blockIdx.x * blockDim.x + threadIdx.x;
  if (i < n) { float f = freqs[i]; cs[i] = make_float2(cosf(f), sinf(f)); }
}

// ---------------- GEMM: C[M,N] = A[M,K] * B[N,K]^T (bf16 in, f32 acc) -------
// 128x128 tile, BK=32, 4 waves (2x2), global_load_lds staging with XOR swizzle.
// EPI==0: plain f32 store to Cout.
// EPI==1: fused qkv split + RoPE + scale, bf16 stores to qo/ko/vo in [bh][n][d].
#define QSCALE 0.18033688011112042f   // (1/8) * log2(e)

template<int EPI>
__global__ __launch_bounds__(256) void gemm_bt(
    const unsigned short* __restrict__ A,
    const unsigned short* __restrict__ Bm,
    int Kdim, int Ncols,
    float* __restrict__ Cout,
    unsigned short* __restrict__ qo, unsigned short* __restrict__ ko,
    unsigned short* __restrict__ vo, const float2* __restrict__ cs)
{
  __shared__ __align__(16) unsigned short Al[128 * 32];
  __shared__ __align__(16) unsigned short Bl[128 * 32];
  const int t = threadIdx.x;
  const int w = t >> 6, lane = t & 63, lr = lane & 15, g = lane >> 4;
  const int m0 = blockIdx.y * 128;
  const int n0 = blockIdx.x * 128;
  const int wm = w >> 1, wn = w & 1;
  const int xs = (lr & 3) ^ ((lr >> 2) & 3);   // read-side XOR swizzle term

  f32x4 acc[4][4];
  f32x4 zero = {0.0f, 0.0f, 0.0f, 0.0f};
  #pragma unroll
  for (int i = 0; i < 4; i++)
    #pragma unroll
    for (int j = 0; j < 4; j++) acc[i][j] = zero;

  // staging geometry: chunk c covers LDS bytes [c*4096 + t*16, +16)
  int roww[2], swo[2];
  #pragma unroll
  for (int c = 0; c < 2; c++) {
    int off = c * 4096 + t * 16;
    int row = off >> 6;                    // 32 bf16 (64B) per row
    int col16 = (off >> 4) & 3;            // 16B chunk within row
    int sw = col16 ^ ((row & 3) ^ ((row >> 2) & 3));  // write-side inverse swizzle
    roww[c] = row; swo[c] = sw * 8;
  }

  for (int k0 = 0; k0 < Kdim; k0 += 32) {
    #pragma unroll
    for (int c = 0; c < 2; c++) {
      const unsigned short* sa = A  + (size_t)(m0 + roww[c]) * Kdim + k0 + swo[c];
      const unsigned short* sb = Bm + (size_t)(n0 + roww[c]) * Kdim + k0 + swo[c];
      __builtin_amdgcn_global_load_lds(
          (const __attribute__((address_space(1))) void*)sa,
          (__attribute__((address_space(3))) void*)(Al + c * 2048 + w * 512), 16, 0, 0);
      __builtin_amdgcn_global_load_lds(
          (const __attribute__((address_space(1))) void*)sb,
          (__attribute__((address_space(3))) void*)(Bl + c * 2048 + w * 512), 16, 0, 0);
    }
    __syncthreads();

    short8 af[4], bfr[4];
    #pragma unroll
    for (int m = 0; m < 4; m++) {
      int row = wm * 64 + m * 16 + lr;
      af[m] = *(const short8*)&Al[row * 32 + (g ^ xs) * 8];
    }
    #pragma unroll
    for (int n = 0; n < 4; n++) {
      int row = wn * 64 + n * 16 + lr;
      bfr[n] = *(const short8*)&Bl[row * 32 + (g ^ xs) * 8];
    }
    #pragma unroll
    for (int m = 0; m < 4; m++)
      #pragma unroll
      for (int n = 0; n < 4; n++)
        acc[m][n] = __builtin_amdgcn_mfma_f32_16x16x32_bf16(af[m], bfr[n], acc[m][n], 0, 0, 0);
    __syncthreads();
  }

  if (EPI == 0) {
    #pragma unroll
    for (int m = 0; m < 4; m++) {
      #pragma unroll
      for (int r = 0; r < 4; r++) {
        int row = m0 + wm * 64 + m * 16 + g * 4 + r;
        #pragma unroll
        for (int n = 0; n < 4; n++) {
          int col = n0 + wn * 64 + n * 16 + lr;
          Cout[(size_t)row * Ncols + col] = acc[m][n][r];
        }
      }
    }
  } else {
    const int which = n0 >> 11;                       // 0:q 1:k 2:v
    const int colbase = (n0 + wn * 64) & 2047;        // 64-aligned
    const int head = colbase >> 6;
    #pragma unroll
    for (int m = 0; m < 4; m++) {
      #pragma unroll
      for (int r = 0; r < 4; r++) {
        int row = m0 + wm * 64 + m * 16 + g * 4 + r;
        int b = row >> 11, ntok = row & 2047;
        size_t obase = ((size_t)(b * NH + head) * NSEQ + ntok) * DH;
        #pragma unroll
        for (int n = 0; n < 4; n++) {
          int d = n * 16 + lr;
          float val = acc[m][n][r];
          if (which == 2) {
            vo[obase + d] = f2bf(val);
          } else {
            float other = acc[m][n ^ 2][r];           // partner d^32
            float2 c2 = cs[ntok * DH + d];
            float rot = (d < 32) ? (val * c2.x - other * c2.y)
                                 : (val * c2.x + other * c2.y);
            if (which == 0) qo[obase + d] = f2bf(rot * QSCALE);
            else            ko[obase + d] = f2bf(rot);
          }
        }
      }
    }
  }
}

// ---------------- flash attention: per (q-tile 64, bh) ----------------------
// 4 waves, 16 q-rows/wave. KV chunk 128 staged in LDS. 16x16x32 bf16 MFMA.
__global__ __launch_bounds__(256) void attn_fa(
    const unsigned short* __restrict__ qb,
    const unsigned short* __restrict__ kb,
    const unsigned short* __restrict__ vb,
    unsigned short* __restrict__ aob)
{
  __shared__ __align__(16) unsigned short Kl[128 * 72];   // [kk][64+pad8]
  __shared__ __align__(16) unsigned short Vt[64 * 136];   // [dv][128+pad8]
  __shared__ __align__(16) unsigned short Pl[4][16 * 72]; // per-wave [q][64+pad8]

  const int t = threadIdx.x;
  const int w = t >> 6, lane = t & 63, lr = lane & 15, g = lane >> 4;
  const int bh = blockIdx.y;
  const int q0 = blockIdx.x * 64 + w * 16;
  const size_t hbase = (size_t)bh * NSEQ * DH;

  short8 qf0 = *(const short8*)(qb + hbase + (size_t)(q0 + lr) * DH + g * 8);
  short8 qf1 = *(const short8*)(qb + hbase + (size_t)(q0 + lr) * DH + 32 + g * 8);

  f32x4 zero = {0.0f, 0.0f, 0.0f, 0.0f};
  f32x4 oacc[4];
  #pragma unroll
  for (int i = 0; i < 4; i++) oacc[i] = zero;
  float mrun[4], lrun[4];
  #pragma unroll
  for (int r = 0; r < 4; r++) { mrun[r] = -1e30f; lrun[r] = 0.0f; }

  for (int kv0 = 0; kv0 < NSEQ; kv0 += 128) {
    __syncthreads();
    { // stage K chunk [128][64] -> Kl
      int row = t >> 1, hf = (t & 1) * 32;
      const unsigned short* src = kb + hbase + (size_t)(kv0 + row) * DH + hf;
      unsigned short* dst = &Kl[row * 72 + hf];
      *(short8*)(dst)      = *(const short8*)(src);
      *(short8*)(dst + 8)  = *(const short8*)(src + 8);
      *(short8*)(dst + 16) = *(const short8*)(src + 16);
      *(short8*)(dst + 24) = *(const short8*)(src + 24);
    }
    { // stage V chunk transposed -> Vt[dv][kk]
      int r0 = (t & 63) * 2;
      int hv = (t >> 6) * 16;
      const unsigned short* s0 = vb + hbase + (size_t)(kv0 + r0) * DH + hv;
      short8 v0a = *(const short8*)(s0);
      short8 v0b = *(const short8*)(s0 + 8);
      short8 v1a = *(const short8*)(s0 + DH);
      short8 v1b = *(const short8*)(s0 + DH + 8);
      #pragma unroll
      for (int j = 0; j < 8; j++) {
        unsigned int p0 = ((unsigned short)v0a[j]) | (((unsigned int)(unsigned short)v1a[j]) << 16);
        *(unsigned int*)&Vt[(hv + j) * 136 + r0] = p0;
        unsigned int p1 = ((unsigned short)v0b[j]) | (((unsigned int)(unsigned short)v1b[j]) << 16);
        *(unsigned int*)&Vt[(hv + 8 + j) * 136 + r0] = p1;
      }
    }
    __syncthreads();

    #pragma unroll
    for (int kv1 = 0; kv1 < 128; kv1 += 64) {
      // ---- QK^T: scores for 16q x 64kk ----
      f32x4 s[4];
      #pragma unroll
      for (int kt = 0; kt < 4; kt++) {
        const unsigned short* kp = &Kl[(kv1 + kt * 16 + lr) * 72 + g * 8];
        short8 kA = *(const short8*)(kp);
        short8 kB = *(const short8*)(kp + 32);
        f32x4 acc0 = __builtin_amdgcn_mfma_f32_16x16x32_bf16(qf0, kA, zero, 0, 0, 0);
        s[kt] = __builtin_amdgcn_mfma_f32_16x16x32_bf16(qf1, kB, acc0, 0, 0, 0);
      }
      // ---- online softmax (base-2 domain; scale*log2e folded into q) ----
      float mn[4], cc[4];
      #pragma unroll
      for (int r = 0; r < 4; r++) {
        float v = fmaxf(fmaxf(s[0][r], s[1][r]), fmaxf(s[2][r], s[3][r]));
        v = fmaxf(v, __shfl_xor(v, 1));
        v = fmaxf(v, __shfl_xor(v, 2));
        v = fmaxf(v, __shfl_xor(v, 4));
        v = fmaxf(v, __shfl_xor(v, 8));
        mn[r] = fmaxf(mrun[r], v);
        cc[r] = exp2f(mrun[r] - mn[r]);
        mrun[r] = mn[r];
      }
      float ls[4] = {0.0f, 0.0f, 0.0f, 0.0f};
      unsigned short pbf[4][4];
      #pragma unroll
      for (int kt = 0; kt < 4; kt++)
        #pragma unroll
        for (int r = 0; r < 4; r++) {
          float p = exp2f(s[kt][r] - mn[r]);
          ls[r] += p;
          pbf[kt][r] = f2bf(p);
        }
      #pragma unroll
      for (int r = 0; r < 4; r++) {
        float v = ls[r];
        v += __shfl_xor(v, 1);
        v += __shfl_xor(v, 2);
        v += __shfl_xor(v, 4);
        v += __shfl_xor(v, 8);
        lrun[r] = lrun[r] * cc[r] + v;
      }
      #pragma unroll
      for (int dv = 0; dv < 4; dv++) {
        f32x4 a = oacc[dv];
        a[0] *= cc[0]; a[1] *= cc[1]; a[2] *= cc[2]; a[3] *= cc[3];
        oacc[dv] = a;
      }
      // ---- P -> LDS (C-layout -> A-layout fix) ----
      #pragma unroll
      for (int kt = 0; kt < 4; kt++)
        #pragma unroll
        for (int r = 0; r < 4; r++)
          Pl[w][(g * 4 + r) * 72 + kt * 16 + lr] = pbf[kt][r];
      // ---- PV ----
      #pragma unroll
      for (int c0 = 0; c0 < 2; c0++) {
        short8 pa = *(const short8*)&Pl[w][lr * 72 + c0 * 32 + g * 8];
        #pragma unroll
        for (int dv = 0; dv < 4; dv++) {
          short8 vf = *(const short8*)&Vt[(dv * 16 + lr) * 136 + kv1 + c0 * 32 + g * 8];
          oacc[dv] = __builtin_amdgcn_mfma_f32_16x16x32_bf16(pa, vf, oacc[dv], 0, 0, 0);
        }
      }
    }
  }

  // epilogue: normalize and store [b][n][h*64+d]
  const int b = bh >> 5, h = bh & 31;
  #pragma unroll
  for (int r = 0; r < 4; r++) {
    int ntok = q0 + g * 4 + r;
    float inv = 1.0f / lrun[r];
    size_t ob = ((size_t)(b * NSEQ + ntok)) * DIMC + h * DH;
    #pragma unroll
    for (int dv = 0; dv < 4; dv++)
      aob[ob + dv * 16 + lr] = f2bf(oacc[dv][r] * inv);
  }
}

// ---------------------------------------------------------------------------
extern "C" void kernel_launch(void* const* d_in, const int* in_sizes, int n_in,
                              void* d_out, int out_size, void* d_ws, size_t ws_size,
                              hipStream_t stream) {
  const float* x     = (const float*)d_in[0];
  const float* freqs = (const float*)d_in[1];
  const float* Wqkv  = (const float*)d_in[2];
  const float* Wout  = (const float*)d_in[3];
  float* out = (float*)d_out;

  char* ws = (char*)d_ws;
  size_t off = 0;
  auto alloc = [&](size_t bytes) {
    void* p = ws + off;
    off += (bytes + 255) & ~(size_t)255;
    return p;
  };
  unsigned short* xb    = (unsigned short*)alloc((size_t)MROWS * DIMC * 2);
  unsigned short* wqkvb = (unsigned short*)alloc((size_t)NQKV * DIMC * 2);
  unsigned short* woutb = (unsigned short*)alloc((size_t)DIMC * DIMC * 2);
  unsigned short* qbuf  = (unsigned short*)alloc((size_t)BHEADS * NSEQ * DH * 2);
  unsigned short* kbuf  = (unsigned short*)alloc((size_t)BHEADS * NSEQ * DH * 2);
  unsigned short* vbuf  = (unsigned short*)alloc((size_t)BHEADS * NSEQ * DH * 2);
  float2* cst           = (float2*)alloc((size_t)NSEQ * DH * sizeof(float2));
  unsigned short* aob   = xb;   // xb is dead after gemm1; reuse for attn output

  cvt_bf16<<<2048, 256, 0, stream>>>(x, xb, MROWS * DIMC / 8);
  cvt_bf16<<<2048, 256, 0, stream>>>(Wqkv, wqkvb, NQKV * DIMC / 8);
  cvt_bf16<<<1024, 256, 0, stream>>>(Wout, woutb, DIMC * DIMC / 8);
  build_cs<<<(NSEQ * DH + 255) / 256, 256, 0, stream>>>(freqs, cst, NSEQ * DH);

  gemm_bt<1><<<dim3(NQKV / 128, MROWS / 128), 256, 0, stream>>>(
      xb, wqkvb, DIMC, NQKV, nullptr, qbuf, kbuf, vbuf, cst);

  attn_fa<<<dim3(NSEQ / 64, BHEADS), 256, 0, stream>>>(qbuf, kbuf, vbuf, aob);

  gemm_bt<0><<<dim3(DIMC / 128, MROWS / 128), 256, 0, stream>>>(
      aob, woutb, DIMC, DIMC, out, nullptr, nullptr, nullptr, nullptr);
}

// Round 2
// 376.733 us; speedup vs baseline: 1.4050x; 1.4050x over previous
//
#include <hip/hip_runtime.h>

#define DIMC 2048
#define NSEQ 2048
#define NBATCH 2
#define NH 32
#define DH 64
#define BHEADS (NBATCH*NH)      // 64
#define MROWS (NBATCH*NSEQ)     // 4096
#define NQKV (3*DIMC)           // 6144

typedef __attribute__((ext_vector_type(8))) short short8;
typedef __attribute__((ext_vector_type(4))) float f32x4;
typedef __attribute__((ext_vector_type(4))) unsigned int uint4v;
typedef __attribute__((ext_vector_type(2))) unsigned int u32x2;

static __device__ __forceinline__ unsigned short f2bf(float f) {
  union { float f; unsigned int u; } v; v.f = f;
  unsigned int r = (v.u + 0x7FFFu + ((v.u >> 16) & 1u)) >> 16;
  return (unsigned short)r;
}

static __device__ __forceinline__ unsigned int cvt_pk_bf16(float lo, float hi) {
  unsigned int r;
  asm("v_cvt_pk_bf16_f32 %0, %1, %2" : "=v"(r) : "v"(lo), "v"(hi));
  return r;
}

// ---------------- fp32 -> bf16 convert (vectorized, grid-stride) ------------
__global__ __launch_bounds__(256) void cvt_bf16(const float* __restrict__ in,
                                                unsigned short* __restrict__ out,
                                                int n8) {
  int i = blockIdx.x * blockDim.x + threadIdx.x;
  int stride = gridDim.x * blockDim.x;
  for (; i < n8; i += stride) {
    const float4* p = (const float4*)in + (size_t)i * 2;
    float4 a = p[0], b = p[1];
    union { unsigned short u[8]; uint4v v; } o;
    o.u[0] = f2bf(a.x); o.u[1] = f2bf(a.y); o.u[2] = f2bf(a.z); o.u[3] = f2bf(a.w);
    o.u[4] = f2bf(b.x); o.u[5] = f2bf(b.y); o.u[6] = f2bf(b.z); o.u[7] = f2bf(b.w);
    *((uint4v*)out + i) = o.v;
  }
}

// ---------------- cos/sin table --------------------------------------------
__global__ __launch_bounds__(256) void build_cs(const float* __restrict__ freqs,
                                                float2* __restrict__ cs, int n) {
  int i = blockIdx.x * blockDim.x + threadIdx.x;
  if (i < n) { float f = freqs[i]; cs[i] = make_float2(cosf(f), sinf(f)); }
}

// ---------------- GEMM: C[M,N] = A[M,K] * B[N,K]^T (bf16 in, f32 acc) -------
#define QSCALE 0.18033688011112042f   // (1/8) * log2(e)

template<int EPI>
__global__ __launch_bounds__(256) void gemm_bt(
    const unsigned short* __restrict__ A,
    const unsigned short* __restrict__ Bm,
    int Kdim, int Ncols,
    float* __restrict__ Cout,
    unsigned short* __restrict__ qo, unsigned short* __restrict__ ko,
    unsigned short* __restrict__ vo, const float2* __restrict__ cs)
{
  __shared__ __align__(16) unsigned short Al[128 * 32];
  __shared__ __align__(16) unsigned short Bl[128 * 32];
  const int t = threadIdx.x;
  const int w = t >> 6, lane = t & 63, lr = lane & 15, g = lane >> 4;
  const int m0 = blockIdx.y * 128;
  const int n0 = blockIdx.x * 128;
  const int wm = w >> 1, wn = w & 1;
  const int xs = (lr & 3) ^ ((lr >> 2) & 3);

  f32x4 acc[4][4];
  f32x4 zero = {0.0f, 0.0f, 0.0f, 0.0f};
  #pragma unroll
  for (int i = 0; i < 4; i++)
    #pragma unroll
    for (int j = 0; j < 4; j++) acc[i][j] = zero;

  int roww[2], swo[2];
  #pragma unroll
  for (int c = 0; c < 2; c++) {
    int off = c * 4096 + t * 16;
    int row = off >> 6;
    int col16 = (off >> 4) & 3;
    int sw = col16 ^ ((row & 3) ^ ((row >> 2) & 3));
    roww[c] = row; swo[c] = sw * 8;
  }

  for (int k0 = 0; k0 < Kdim; k0 += 32) {
    #pragma unroll
    for (int c = 0; c < 2; c++) {
      const unsigned short* sa = A  + (size_t)(m0 + roww[c]) * Kdim + k0 + swo[c];
      const unsigned short* sb = Bm + (size_t)(n0 + roww[c]) * Kdim + k0 + swo[c];
      __builtin_amdgcn_global_load_lds(
          (const __attribute__((address_space(1))) void*)sa,
          (__attribute__((address_space(3))) void*)(Al + c * 2048 + w * 512), 16, 0, 0);
      __builtin_amdgcn_global_load_lds(
          (const __attribute__((address_space(1))) void*)sb,
          (__attribute__((address_space(3))) void*)(Bl + c * 2048 + w * 512), 16, 0, 0);
    }
    __syncthreads();

    short8 af[4], bfr[4];
    #pragma unroll
    for (int m = 0; m < 4; m++) {
      int row = wm * 64 + m * 16 + lr;
      af[m] = *(const short8*)&Al[row * 32 + (g ^ xs) * 8];
    }
    #pragma unroll
    for (int n = 0; n < 4; n++) {
      int row = wn * 64 + n * 16 + lr;
      bfr[n] = *(const short8*)&Bl[row * 32 + (g ^ xs) * 8];
    }
    #pragma unroll
    for (int m = 0; m < 4; m++)
      #pragma unroll
      for (int n = 0; n < 4; n++)
        acc[m][n] = __builtin_amdgcn_mfma_f32_16x16x32_bf16(af[m], bfr[n], acc[m][n], 0, 0, 0);
    __syncthreads();
  }

  if (EPI == 0) {
    #pragma unroll
    for (int m = 0; m < 4; m++) {
      #pragma unroll
      for (int r = 0; r < 4; r++) {
        int row = m0 + wm * 64 + m * 16 + g * 4 + r;
        #pragma unroll
        for (int n = 0; n < 4; n++) {
          int col = n0 + wn * 64 + n * 16 + lr;
          Cout[(size_t)row * Ncols + col] = acc[m][n][r];
        }
      }
    }
  } else {
    const int which = n0 >> 11;
    const int colbase = (n0 + wn * 64) & 2047;
    const int head = colbase >> 6;
    #pragma unroll
    for (int m = 0; m < 4; m++) {
      #pragma unroll
      for (int r = 0; r < 4; r++) {
        int row = m0 + wm * 64 + m * 16 + g * 4 + r;
        int b = row >> 11, ntok = row & 2047;
        size_t obase = ((size_t)(b * NH + head) * NSEQ + ntok) * DH;
        #pragma unroll
        for (int n = 0; n < 4; n++) {
          int d = n * 16 + lr;
          float val = acc[m][n][r];
          if (which == 2) {
            vo[obase + d] = f2bf(val);
          } else {
            float other = acc[m][n ^ 2][r];
            float2 c2 = cs[ntok * DH + d];
            float rot = (d < 32) ? (val * c2.x - other * c2.y)
                                 : (val * c2.x + other * c2.y);
            if (which == 0) qo[obase + d] = f2bf(rot * QSCALE);
            else            ko[obase + d] = f2bf(rot);
          }
        }
      }
    }
  }
}

// ---------------- flash attention v2: 4 waves x 32 q, KVBLK=64 --------------
// Swapped QK^T (S^T, q lane-local) -> in-lane softmax, packed-b64 P, K staged
// via global_load_lds with XOR swizzle, defer-rescale (THR=8, base-2 domain).
__global__ __launch_bounds__(256, 4) void attn_fa(
    const unsigned short* __restrict__ qb,
    const unsigned short* __restrict__ kb,
    const unsigned short* __restrict__ vb,
    unsigned short* __restrict__ aob)
{
  __shared__ __align__(16) unsigned short Kl[64 * 64];      // linear, XOR-swizzled content
  __shared__ __align__(16) unsigned short Vt[64 * 72];      // [d][k + pad8]
  __shared__ __align__(16) unsigned short Pl[4][32 * 72];   // per-wave [q][k + pad8]

  const int t = threadIdx.x;
  const int w = t >> 6, lane = t & 63, lr = lane & 15, g = lane >> 4;
  const int bh = blockIdx.y;
  const int q0 = blockIdx.x * 128 + w * 32;
  const size_t hbase = (size_t)bh * NSEQ * DH;

  // Q fragments (B-operand): qf[qt][dhalf]
  short8 qf[2][2];
  #pragma unroll
  for (int qt = 0; qt < 2; qt++)
    #pragma unroll
    for (int hf = 0; hf < 2; hf++)
      qf[qt][hf] = *(const short8*)(qb + hbase + (size_t)(q0 + qt * 16 + lr) * DH + hf * 32 + g * 8);

  f32x4 zero = {0.0f, 0.0f, 0.0f, 0.0f};
  f32x4 oacc[2][4];
  #pragma unroll
  for (int qt = 0; qt < 2; qt++)
    #pragma unroll
    for (int dv = 0; dv < 4; dv++) oacc[qt][dv] = zero;
  float mrun[2] = {-1e30f, -1e30f};
  float lrun[2] = {0.0f, 0.0f};

  // K staging geometry: LDS linear byte b -> global element, inverse-swizzled
  int kro[2], kdo_[2];
  #pragma unroll
  for (int c = 0; c < 2; c++) {
    int b = w * 2048 + c * 1024 + lane * 16;
    int row = b >> 7;
    int off = b ^ ((row & 7) << 4);
    kro[c] = row;
    kdo_[c] = (off >> 1) & 63;
  }
  // V staging geometry (register transpose)
  const int vr0 = (t & 31) * 2;
  const int vhv = (t >> 5) * 8;

  unsigned short* prow0 = &Pl[w][lr * 72];
  unsigned short* prow1 = &Pl[w][(16 + lr) * 72];

  for (int kv0 = 0; kv0 < NSEQ; kv0 += 64) {
    __syncthreads();
    // stage K (swizzled, direct-to-LDS)
    #pragma unroll
    for (int c = 0; c < 2; c++) {
      const unsigned short* src = kb + hbase + (size_t)(kv0 + kro[c]) * DH + kdo_[c];
      __builtin_amdgcn_global_load_lds(
          (const __attribute__((address_space(1))) void*)src,
          (__attribute__((address_space(3))) void*)(Kl + w * 1024 + c * 512), 16, 0, 0);
    }
    // stage V transposed: Vt[d][k]
    {
      const unsigned short* s0 = vb + hbase + (size_t)(kv0 + vr0) * DH + vhv;
      short8 v0 = *(const short8*)(s0);
      short8 v1 = *(const short8*)(s0 + DH);
      #pragma unroll
      for (int j = 0; j < 8; j++) {
        unsigned int p = ((unsigned short)v0[j]) | (((unsigned int)(unsigned short)v1[j]) << 16);
        *(unsigned int*)&Vt[(vhv + j) * 72 + vr0] = p;
      }
    }
    __syncthreads();

    // ---- QK^T swapped: S^T[k][q], col=q=lr, row=k=g*4+r (+16*kt) ----
    f32x4 s[2][4];
    #pragma unroll
    for (int kt = 0; kt < 4; kt++) {
      int row = kt * 16 + lr;
      int sw = (row & 7) << 4;
      int byteA = (row * 128 + g * 16) ^ sw;
      int byteB = (row * 128 + 64 + g * 16) ^ sw;
      short8 kA = *(const short8*)((const char*)Kl + byteA);
      short8 kB = *(const short8*)((const char*)Kl + byteB);
      #pragma unroll
      for (int qt = 0; qt < 2; qt++) {
        f32x4 a0 = __builtin_amdgcn_mfma_f32_16x16x32_bf16(kA, qf[qt][0], zero, 0, 0, 0);
        s[qt][kt] = __builtin_amdgcn_mfma_f32_16x16x32_bf16(kB, qf[qt][1], a0, 0, 0, 0);
      }
    }

    // ---- tile max (in-lane 16 + 2 shuffles across g) ----
    float nm[2];
    #pragma unroll
    for (int qt = 0; qt < 2; qt++) {
      f32x4 m01 = s[qt][0];
      #pragma unroll
      for (int kt = 1; kt < 4; kt++) {
        f32x4 sv = s[qt][kt];
        m01[0] = fmaxf(m01[0], sv[0]); m01[1] = fmaxf(m01[1], sv[1]);
        m01[2] = fmaxf(m01[2], sv[2]); m01[3] = fmaxf(m01[3], sv[3]);
      }
      float v = fmaxf(fmaxf(m01[0], m01[1]), fmaxf(m01[2], m01[3]));
      v = fmaxf(v, __shfl_xor(v, 16));
      v = fmaxf(v, __shfl_xor(v, 32));
      nm[qt] = v;
    }

    // ---- defer-rescale (THR=8 in exp2 domain) ----
    if (!__all(fmaxf(nm[0] - mrun[0], nm[1] - mrun[1]) <= 8.0f)) {
      const int sb = (lane & 48) + ((lane & 48) >> 2);   // g*20
      #pragma unroll
      for (int qt = 0; qt < 2; qt++) {
        float m2 = fmaxf(mrun[qt], nm[qt]);
        float cc = exp2f(mrun[qt] - m2);
        mrun[qt] = m2;
        lrun[qt] *= cc;
        float c0r = __shfl(cc, sb + 0);
        float c1r = __shfl(cc, sb + 1);
        float c2r = __shfl(cc, sb + 2);
        float c3r = __shfl(cc, sb + 3);
        #pragma unroll
        for (int dv = 0; dv < 4; dv++) {
          f32x4 a = oacc[qt][dv];
          a[0] *= c0r; a[1] *= c1r; a[2] *= c2r; a[3] *= c3r;
          oacc[qt][dv] = a;
        }
      }
    }

    // ---- P = exp2(S - m), packed bf16 -> LDS (b64 stores) ----
    #pragma unroll
    for (int qt = 0; qt < 2; qt++) {
      float mq = mrun[qt];
      float ls = 0.0f;
      unsigned short* prow = qt ? prow1 : prow0;
      #pragma unroll
      for (int kt = 0; kt < 4; kt++) {
        f32x4 sv = s[qt][kt];
        float p0 = exp2f(sv[0] - mq), p1 = exp2f(sv[1] - mq);
        float p2 = exp2f(sv[2] - mq), p3 = exp2f(sv[3] - mq);
        ls += (p0 + p1) + (p2 + p3);
        u32x2 uu;
        uu.x = cvt_pk_bf16(p0, p1);
        uu.y = cvt_pk_bf16(p2, p3);
        *(u32x2*)(prow + kt * 16 + g * 4) = uu;
      }
      ls += __shfl_xor(ls, 16);
      ls += __shfl_xor(ls, 32);
      lrun[qt] += ls;
    }

    // ---- PV: O[q][d] += P[q][k] * V[k][d] ----
    #pragma unroll
    for (int c0 = 0; c0 < 2; c0++) {
      short8 pa0 = *(const short8*)(prow0 + c0 * 32 + g * 8);
      short8 pa1 = *(const short8*)(prow1 + c0 * 32 + g * 8);
      #pragma unroll
      for (int dv = 0; dv < 4; dv++) {
        short8 vf = *(const short8*)&Vt[(dv * 16 + lr) * 72 + c0 * 32 + g * 8];
        oacc[0][dv] = __builtin_amdgcn_mfma_f32_16x16x32_bf16(pa0, vf, oacc[0][dv], 0, 0, 0);
        oacc[1][dv] = __builtin_amdgcn_mfma_f32_16x16x32_bf16(pa1, vf, oacc[1][dv], 0, 0, 0);
      }
    }
  }

  // ---- epilogue: normalize (transpose 1/l to row domain) and store ----
  const int b = bh >> 5, h = bh & 31;
  const int sb = (lane & 48) + ((lane & 48) >> 2);
  #pragma unroll
  for (int qt = 0; qt < 2; qt++) {
    float inv = 1.0f / lrun[qt];
    float ir[4];
    ir[0] = __shfl(inv, sb + 0);
    ir[1] = __shfl(inv, sb + 1);
    ir[2] = __shfl(inv, sb + 2);
    ir[3] = __shfl(inv, sb + 3);
    #pragma unroll
    for (int r = 0; r < 4; r++) {
      int ntok = q0 + qt * 16 + g * 4 + r;
      size_t ob = ((size_t)(b * NSEQ + ntok)) * DIMC + h * DH;
      #pragma unroll
      for (int dv = 0; dv < 4; dv++)
        aob[ob + dv * 16 + lr] = f2bf(oacc[qt][dv][r] * ir[r]);
    }
  }
}

// ---------------------------------------------------------------------------
extern "C" void kernel_launch(void* const* d_in, const int* in_sizes, int n_in,
                              void* d_out, int out_size, void* d_ws, size_t ws_size,
                              hipStream_t stream) {
  const float* x     = (const float*)d_in[0];
  const float* freqs = (const float*)d_in[1];
  const float* Wqkv  = (const float*)d_in[2];
  const float* Wout  = (const float*)d_in[3];
  float* out = (float*)d_out;

  char* ws = (char*)d_ws;
  size_t off = 0;
  auto alloc = [&](size_t bytes) {
    void* p = ws + off;
    off += (bytes + 255) & ~(size_t)255;
    return p;
  };
  unsigned short* xb    = (unsigned short*)alloc((size_t)MROWS * DIMC * 2);
  unsigned short* wqkvb = (unsigned short*)alloc((size_t)NQKV * DIMC * 2);
  unsigned short* woutb = (unsigned short*)alloc((size_t)DIMC * DIMC * 2);
  unsigned short* qbuf  = (unsigned short*)alloc((size_t)BHEADS * NSEQ * DH * 2);
  unsigned short* kbuf  = (unsigned short*)alloc((size_t)BHEADS * NSEQ * DH * 2);
  unsigned short* vbuf  = (unsigned short*)alloc((size_t)BHEADS * NSEQ * DH * 2);
  float2* cst           = (float2*)alloc((size_t)NSEQ * DH * sizeof(float2));
  unsigned short* aob   = xb;   // xb dead after gemm1; reuse for attn output

  cvt_bf16<<<2048, 256, 0, stream>>>(x, xb, MROWS * DIMC / 8);
  cvt_bf16<<<2048, 256, 0, stream>>>(Wqkv, wqkvb, NQKV * DIMC / 8);
  cvt_bf16<<<1024, 256, 0, stream>>>(Wout, woutb, DIMC * DIMC / 8);
  build_cs<<<(NSEQ * DH + 255) / 256, 256, 0, stream>>>(freqs, cst, NSEQ * DH);

  gemm_bt<1><<<dim3(NQKV / 128, MROWS / 128), 256, 0, stream>>>(
      xb, wqkvb, DIMC, NQKV, nullptr, qbuf, kbuf, vbuf, cst);

  attn_fa<<<dim3(NSEQ / 128, BHEADS), 256, 0, stream>>>(qbuf, kbuf, vbuf, aob);

  gemm_bt<0><<<dim3(DIMC / 128, MROWS / 128), 256, 0, stream>>>(
      aob, woutb, DIMC, DIMC, out, nullptr, nullptr, nullptr, nullptr);
}